// Round 3
// baseline (101.933 us; speedup 1.0000x reference)
//
#include <hip/hip_runtime.h>
#include <hip/hip_bf16.h>

// Model_10514079940941 — fp32 in / fp32 out.
// R13: cooperative conv-weight loading. R12's wcv[75] scatter prefetch
// (64 distinct lines per wave-instruction, ~15k TA lookups/block) replaced
// by 4-lane-per-filter cooperative dword loads: group gid=t/4 owns filter
// f=gid+64r (4 rounds), lane li=t&3 loads elems li+4i — 16B contiguous per
// group => ~16-20 lines/instr, ~3.8x fewer TA lookups, -37 VGPR, no
// alignment risk. Rounds 0/1 prefetched early (drain under Phase 0/1, R12
// FIFO discipline), rounds 2/3 pipelined in Phase B. simg read once into
// sv[19] regs, reused all rounds. 4-lane shfl_xor reduce per filter.
// GPB=2 (512 blocks, 2/CU) — R11 showed 4/block regresses.
// Cull (verified R6-R9): q>100 => contribution < 1e-13 at 4.4e-2 threshold.

#define NG 1024
#define GPB 2

__device__ __forceinline__ float tanh_fast(float x) {
    return 1.0f - 2.0f / (__expf(2.0f * x) + 1.0f);
}

__global__ __launch_bounds__(256, 2) void k_fused(
    const float* __restrict__ means, const float* __restrict__ u,
    const float* __restrict__ scal, const float* __restrict__ trans,
    const float* __restrict__ opac,
    const float* __restrict__ convW, const float* __restrict__ convb,
    const float* __restrict__ embW,  const float* __restrict__ embb,
    const float* __restrict__ l1W,   const float* __restrict__ l1b,
    const float* __restrict__ oWs,  const float* __restrict__ obs,
    const float* __restrict__ oWt,  const float* __restrict__ obt,
    const float* __restrict__ oWsc, const float* __restrict__ obsc,
    const float* __restrict__ oWtf, const float* __restrict__ obtf,
    float* __restrict__ out)
{
    __shared__ __align__(16) float gcomp[NG * 8];   // worst case: 32 KB
    __shared__ float pus[2][2][32];
    __shared__ float plap[2][2][32];
    __shared__ float2 simgv[80];       // [sample-feature] x {gauss0, gauss1}
    __shared__ float2 hinv[4][80];     // [k][feature] x {g0, g1}
    __shared__ float2 hvv[4 * 81];     // [k][g] padded to 81
    __shared__ float semb[840];        // embW copy
    __shared__ float sembb[120];
    __shared__ float shead[480];       // oWs(80)|oWt(160)|oWsc(160)|oWtf(80)
    __shared__ float sheadb[6];
    __shared__ int   cnt;

    const int t  = threadIdx.x;
    const int n0 = blockIdx.x * GPB;
    const int gid = t >> 2, li = t & 3;

    // ---- (1) cull inputs -> registers. FIRST in the VMEM FIFO. -------------
    float2 gm[4], gs[4];
    float  gt[4], go[4], gu[4];
    #pragma unroll
    for (int i = 0; i < 4; ++i) {
        int g = t + 256 * i;
        gm[i] = *(const float2*)(means + 2 * g);
        gs[i] = *(const float2*)(scal  + 2 * g);
        gt[i] = trans[g];
        go[i] = opac[g];
        gu[i] = u[g];
    }

    // ---- (2) small-weight staging -> registers (retire early in FIFO) ------
    float se0 = embW[t];
    float se1 = embW[256 + t];
    float se2 = embW[512 + t];
    float se3 = (t < 72)  ? embW[768 + t] : 0.0f;
    float sbb = (t < 120) ? embb[t] : 0.0f;
    float sh0 = (t < 80)  ? oWs[t] : (t < 240) ? oWt[t - 80] : oWsc[t - 240];
    float sh1 = 0.0f;
    if (t < 224) sh1 = (t < 144) ? oWsc[t + 16] : oWtf[t - 144]; // i=256+t
    float shb = 0.0f;
    if (t < 6) shb = (t == 0) ? obs[0] : (t < 3) ? obt[t-1]
                   : (t < 5) ? obsc[t-3] : obtf[0];

    // ---- wave-uniform scalar loads (s_load path, lgkmcnt — independent) ----
    const float mx0 = means[2*n0],   my0 = means[2*n0+1];
    const float mx1 = means[2*n0+2], my1 = means[2*n0+3];
    const float uu0 = u[n0],     uu1 = u[n0+1];
    const float sc00 = scal[2*n0],   sc01 = scal[2*n0+1];
    const float sc10 = scal[2*n0+2], sc11 = scal[2*n0+3];
    const float tr0 = trans[n0], tr1 = trans[n0+1];
    const float op0 = opac[n0],  op1 = opac[n0+1];

    // ---- (3) l1 weight register prefetch (coalesced, awaited at Phase C) ---
    float wl1[80];
    {
        int k = t / 80, g = t - (t / 80) * 80;
        const float* w = l1W + (size_t)(k * 80) * 80 + g;
        #pragma unroll
        for (int f = 0; f < 80; ++f) wl1[f] = w[f * 80];
    }
    float b1   = l1b[t];
    float b1k3 = l1b[256 + (t & 63)];          // bias for l1 outputs 256..319

    // ---- (4) conv rounds 0/1 prefetch: cooperative 4-lane-per-filter -------
    float wa[19], wb[19];
    {
        const float* r0 = convW + gid * 75 + li;          // f = gid
        #pragma unroll
        for (int i = 0; i < 18; ++i) wa[i] = r0[4*i];
        wa[18] = (li < 3) ? r0[72] : 0.0f;
        const float* r1 = convW + (gid + 64) * 75 + li;   // f = gid+64
        #pragma unroll
        for (int i = 0; i < 18; ++i) wb[i] = r1[4*i];
        wb[18] = (li < 3) ? r1[72] : 0.0f;
    }
    float cb0 = convb[gid];
    float cb1 = convb[gid + 64];
    float cb2 = convb[gid + 128];
    float cb3 = (gid < 8) ? convb[gid + 192] : 0.0f;

    const float bxmin = fminf(mx0, mx1) - 0.02f, bxmax = fmaxf(mx0, mx1) + 0.02f;
    const float bymin = fminf(my0, my1) - 0.02f, bymax = fmaxf(my0, my1) + 0.02f;

    // ---- staging regs -> LDS (waits only on early FIFO entries) ------------
    semb[t]       = se0;
    semb[256 + t] = se1;
    semb[512 + t] = se2;
    if (t < 72)  semb[768 + t] = se3;
    if (t < 120) sembb[t] = sbb;
    shead[t] = sh0;
    if (t < 224) shead[256 + t] = sh1;
    if (t < 6)   sheadb[t] = shb;

    if (t == 0) cnt = 0;
    __syncthreads();

    // ---- Phase 0: cull from registers; conic only for survivors ------------
    #pragma unroll
    for (int i = 0; i < 4; ++i) {
        float gmx = gm[i].x, gmy = gm[i].y;
        float s0  = gs[i].x, s1  = gs[i].y;
        float tt  = gt[i];
        float c00 = s0*s0, c01 = s0*tt, c11 = tt*tt + s1*s1;
        float r2  = 100.0f * (c00 + c11);          // q>100 culled
        float ddx = fmaxf(fmaxf(bxmin - gmx, gmx - bxmax), 0.0f);
        float ddy = fmaxf(fmaxf(bymin - gmy, gmy - bymax), 0.0f);
        if (ddx*ddx + ddy*ddy <= r2) {
            float idet = 1.0f / (c00*c11 - c01*c01);
            float A = c11*idet, B = -c01*idet, C = c00*idet;
            float alpha = 1.0f / (1.0f + __expf(-go[i]));
            int slot = atomicAdd(&cnt, 1);
            float4* dst = (float4*)(gcomp + slot*8);
            dst[0] = make_float4(gmx, gmy, A, B);
            dst[1] = make_float4(C, A + C, alpha * gu[i], 0.0f);
        }
    }
    __syncthreads();
    const int nsurv = cnt;

    // ---- Phase 1: pairwise. wave w: gaussian l=w>>1; chunk=(w&1)*2+lanehalf.
    {
        int w = t >> 6, lane = t & 63;
        int l = w >> 1;
        int hc = ((w & 1) << 1) | (lane >> 5);
        int s  = lane & 31; if (s > 24) s = 24;     // lanes 25-31 redundant
        int si = s / 5, sj = s - si * 5;
        float gx = l ? mx1 : mx0, gy = l ? my1 : my0;
        float sx = gx + (float)(si - 2) * 0.01f;
        float sy = gy + (float)(sj - 2) * 0.01f;
        float us = 0.0f, lp = 0.0f;
        #pragma unroll 2
        for (int i = hc; i < nsurv; i += 4) {
            float4 a = *(const float4*)(gcomp + i*8);
            float4 b = *(const float4*)(gcomp + i*8 + 4);
            float dx = sx - a.x, dy = sy - a.y;
            float Cq0 = a.z*dx + a.w*dy;
            float Cq1 = a.w*dx + b.x*dy;
            float q   = dx*Cq0 + dy*Cq1;
            float e   = __expf(-0.5f*q) * b.z;     // G * alpha * u
            us += e;
            lp += e * (Cq0*Cq0 + Cq1*Cq1 - b.y);
        }
        us += __shfl_down(us, 32);                 // combine lane-half chunks
        lp += __shfl_down(lp, 32);
        if ((lane & 31) == s && lane < 32) {       // lanes 0..24 only
            pus[l][w & 1][s] = us; plap[l][w & 1][s] = lp;
        }
    }
    __syncthreads();

    // ---- Phase A: combine 2 wave-partials -> simg, float2-over-gaussian ----
    if (t < 50) {
        int l = t / 25, s = t - l * 25;
        float us = pus[l][0][s] + pus[l][1][s];
        float lp = plap[l][0][s] + plap[l][1][s];
        int si = s / 5, sj = s - si * 5;
        float gx = l ? mx1 : mx0, gy = l ? my1 : my0;
        float sx = gx + (float)(si - 2) * 0.01f;
        float sy = gy + (float)(sj - 2) * 0.01f;
        float* sg = (float*)simgv;
        sg[(s)*2 + l]      = us;
        sg[(25 + s)*2 + l] = lp;
        sg[(50 + s)*2 + l] = (fabsf(sx) < 1.0f && fabsf(sy) < 1.0f) ? 1.0f : 0.0f;
    }
    __syncthreads();

    // ---- Phase B: cooperative conv (4 lanes/filter, 4 rounds) + emb --------
#define CONV_ROUND(BUF, FF, CB)                                           \
    {                                                                     \
        float a0 = 0.0f, a1 = 0.0f;                                       \
        _Pragma("unroll")                                                 \
        for (int i = 0; i < 19; ++i) {                                    \
            a0 += sv[i].x * BUF[i];                                       \
            a1 += sv[i].y * BUF[i];                                       \
        }                                                                 \
        a0 += __shfl_xor(a0, 1); a0 += __shfl_xor(a0, 2);                 \
        a1 += __shfl_xor(a1, 1); a1 += __shfl_xor(a1, 2);                 \
        if (li == 0) {                                                    \
            int ff = (FF);                                                \
            hinv[ff / 50][ff % 50] =                                      \
                make_float2(tanh_fast(a0 + (CB)), tanh_fast(a1 + (CB))); \
        }                                                                 \
    }
    {
        float2 sv[19];
        #pragma unroll
        for (int i = 0; i < 19; ++i) {
            int j = li + 4 * i;
            sv[i] = simgv[j > 74 ? 74 : j];        // li=3,i=18: weight is 0
        }
        CONV_ROUND(wa, gid, cb0)                   // round 0 (prefetched)
        {                                          // prefetch round 2 -> wa
            const float* r2 = convW + (gid + 128) * 75 + li;
            #pragma unroll
            for (int i = 0; i < 18; ++i) wa[i] = r2[4*i];
            wa[18] = (li < 3) ? r2[72] : 0.0f;
        }
        CONV_ROUND(wb, gid + 64, cb1)              // round 1 (prefetched)
        if (gid < 8) {                             // prefetch round 3 -> wb
            const float* r3 = convW + (gid + 192) * 75 + li;
            #pragma unroll
            for (int i = 0; i < 18; ++i) wb[i] = r3[4*i];
            wb[18] = (li < 3) ? r3[72] : 0.0f;
        }
        CONV_ROUND(wa, gid + 128, cb2)             // round 2
        if (gid < 8) {
            CONV_ROUND(wb, gid + 192, cb3)         // round 3 (filters 192-199)
        }
    }
#undef CONV_ROUND
    if (t < 240) {                                 // emb: 2 gauss x 4 k x 30
        int l = t / 120, rem = t - l * 120;
        int k = rem / 30, g = rem - k * 30;
        float acc = sembb[k * 30 + g];
        #pragma unroll
        for (int f = 0; f < 7; ++f) {
            float in0, in1;
            switch (f) {
                case 0: in0 = mx0;  in1 = mx1;  break;
                case 1: in0 = my0;  in1 = my1;  break;
                case 2: in0 = uu0;  in1 = uu1;  break;
                case 3: in0 = sc00; in1 = sc10; break;
                case 4: in0 = sc01; in1 = sc11; break;
                case 5: in0 = tr0;  in1 = tr1;  break;
                default: in0 = op0; in1 = op1;  break;
            }
            acc += (l ? in1 : in0) * semb[(k*7 + f)*30 + g];
        }
        ((float*)hinv)[(k*80 + 50 + g)*2 + l] = tanh_fast(acc);
    }
    __syncthreads();

    // ---- Phase C: l1. Outputs 0..255 from registers; 256..319 from L2 ------
    {
        int k = t / 80, g = t - (t / 80) * 80;
        float a0 = b1, a1 = b1;
        #pragma unroll
        for (int f = 0; f < 80; ++f) {
            float2 h = hinv[k][f];                 // broadcast b64
            a0 += h.x * wl1[f];
            a1 += h.y * wl1[f];
        }
        hvv[k*81 + g] = make_float2(tanh_fast(a0), tanh_fast(a1));
    }
    if (t < 64) {                                   // outputs 256..319: k=3
        int g = 16 + t;
        float a0 = b1k3, a1 = b1k3;
        #pragma unroll 8
        for (int f = 0; f < 80; ++f) {
            float w = l1W[(3*80 + f)*80 + g];
            float2 h = hinv[3][f];
            a0 += h.x * w;
            a1 += h.y * w;
        }
        hvv[3*81 + g] = make_float2(tanh_fast(a0), tanh_fast(a1));
    }
    __syncthreads();

    // ---- Phase D+E: heads from LDS + finalize, wave 0, shfl gather ---------
    if (t < 64) {
        int l = (t / 6) & 1, t6 = t % 6;            // lanes 12-63 redundant
        int k, base, stride, j;
        if (t6 == 0)      { k = 0; base = 0;   stride = 1; j = 0; }
        else if (t6 < 3)  { k = 1; base = 80;  stride = 2; j = t6 - 1; }
        else if (t6 < 5)  { k = 2; base = 240; stride = 2; j = t6 - 3; }
        else              { k = 3; base = 400; stride = 1; j = 0; }
        float acc = sheadb[t6];
        const float* hvf = (const float*)hvv;
        #pragma unroll 8
        for (int f = 0; f < 80; ++f)
            acc += hvf[(k*81 + f)*2 + l] * shead[base + f * stride + j];

        int sb = (t / 6) * 6;
        float o0 = __shfl(acc, sb + 0);
        float o1 = __shfl(acc, sb + 1);
        float o2 = __shfl(acc, sb + 2);
        float o3 = __shfl(acc, sb + 3);
        float o4 = __shfl(acc, sb + 4);
        float o5 = __shfl(acc, sb + 5);

        if (t == 0 || t == 6) {
            int n = n0 + (t / 6);
            float uu = t ? uu1 : uu0;
            float s0 = t ? sc10 : sc00, s1 = t ? sc11 : sc01;
            float tr = t ? tr1 : tr0;
            float u_new = uu + o0;
            float mxn = (t ? mx1 : mx0) + o1;
            float myn = (t ? my1 : my0) + o2;
            float s0n = s0 * __expf(o3);
            float s1n = s1 * __expf(o4);
            float tn  = tr + o5;
            float c00 = s0n*s0n, c01 = s0n*tn, c11 = tn*tn + s1n*s1n;
            out[n]              = u_new;   // u_new         @0
            out[1024 + 2*n]     = mxn;     // means_new     @1024
            out[1024 + 2*n + 1] = myn;
            out[3072 + 2*n]     = s0n;     // scaling_new   @3072
            out[3072 + 2*n + 1] = s1n;
            out[5120 + n]       = tn;      // transform_new @5120
            out[6144 + 4*n]     = c00;     // cov_new       @6144
            out[6144 + 4*n + 1] = c01;
            out[6144 + 4*n + 2] = c01;
            out[6144 + 4*n + 3] = c11;
        }
    }
}

// ---------------------------------------------------------------- launch
extern "C" void kernel_launch(void* const* d_in, const int* in_sizes, int n_in,
                              void* d_out, int out_size, void* d_ws, size_t ws_size,
                              hipStream_t stream)
{
    k_fused<<<dim3(NG / GPB), dim3(256), 0, stream>>>(
        (const float*)d_in[0],  (const float*)d_in[1],  (const float*)d_in[2],
        (const float*)d_in[3],  (const float*)d_in[4],  (const float*)d_in[5],
        (const float*)d_in[6],  (const float*)d_in[7],  (const float*)d_in[8],
        (const float*)d_in[9],  (const float*)d_in[10], (const float*)d_in[11],
        (const float*)d_in[12], (const float*)d_in[13], (const float*)d_in[14],
        (const float*)d_in[15], (const float*)d_in[16], (const float*)d_in[17],
        (const float*)d_in[18], (float*)d_out);
}